// Round 3
// baseline (873.813 us; speedup 1.0000x reference)
//
#include <hip/hip_runtime.h>
#include <hip/hip_bf16.h>

typedef __attribute__((ext_vector_type(8))) __bf16 bf16x8;
typedef __attribute__((ext_vector_type(4))) float f32x4;

#define SEQ 2048
#define BATCH 2
#define LDQ 6144   // QKV row stride: 32 Q heads | 8 K heads | 8 V heads

// ---------------------------------------------------------------------------
// helpers
// ---------------------------------------------------------------------------
__device__ __forceinline__ void stc(float* p, float v)          { *p = v; }
__device__ __forceinline__ void stc(__hip_bfloat16* p, float v) { *p = __float2bfloat16(v); }

// async 16B global->LDS. ldsptr MUST be wave-uniform; HW writes base + lane*16.
__device__ __forceinline__ void async_copy16(const __hip_bfloat16* g, __hip_bfloat16* lds) {
    __builtin_amdgcn_global_load_lds(
        (const __attribute__((address_space(1))) unsigned int*)g,
        (__attribute__((address_space(3))) unsigned int*)lds,
        16, 0, 0);
}

// ---------------------------------------------------------------------------
// fp32 -> bf16 conversion (vectorized, 8 elems/thread)
// ---------------------------------------------------------------------------
__global__ void f2b_kernel(const float* __restrict__ s, __hip_bfloat16* __restrict__ d, int n8)
{
    const int i = blockIdx.x * blockDim.x + threadIdx.x;
    if (i >= n8) return;
    const float4 a = ((const float4*)s)[i * 2];
    const float4 b = ((const float4*)s)[i * 2 + 1];
    __hip_bfloat16 t[8];
    t[0] = __float2bfloat16(a.x); t[1] = __float2bfloat16(a.y);
    t[2] = __float2bfloat16(a.z); t[3] = __float2bfloat16(a.w);
    t[4] = __float2bfloat16(b.x); t[5] = __float2bfloat16(b.y);
    t[6] = __float2bfloat16(b.z); t[7] = __float2bfloat16(b.w);
    ((uint4*)d)[i] = *(const uint4*)t;
}

// ---------------------------------------------------------------------------
// GEMM: C[M,N] = A[M,K] @ B[N,K]^T  (bf16 in, fp32 acc) — 256x256 8-phase
// schedule (m201 structure): BK=64, 512 thr = 8 waves (2Mx4N), per-wave
// output 128x64. LDS 128KB = 2 dbuf x {A,B} x {k0,k1} x [256][32] bf16.
// K-split [256][32] units: 64B row stride -> ds_read_b128 bank-uniform,
// global_load_lds dest linear (rule 21 safe).
//
// TWO-LOOSE-WAIT pipeline (r3): every vmcnt targets loads issued 4 phases
// earlier (never 2.5 like the old single q3 wait):
//   W1 @q1-end: vmcnt(8) -> tile T's kh1 units (issued T-1 q0/q1) landed;
//               needed by q2/q3 ds_reads.
//   W2 @q3-end: vmcnt(8) -> tile T+1's kh0 units (issued T-1 q2/q3) landed;
//               needed by T+1 q0/q1 ds_reads.
// In-flight after each wait = 8 insts (4 units). Tail: T=NT-2 W2->vmcnt(4)
// (q2/q3 stage nothing), T=NT-1 W1->vmcnt(0), W2 none. vmcnt retires
// in-order (m135), so "8 insts issued after unit U" == U landed.
// ---------------------------------------------------------------------------
template<typename TC>
__global__ __launch_bounds__(512, 2) void gemm256_kernel(
    const __hip_bfloat16* __restrict__ A,
    const __hip_bfloat16* __restrict__ B,
    TC* __restrict__ C,
    int M, int N, int K)
{
    __shared__ __align__(16) __hip_bfloat16 sAB[2][2][2][256][32]; // [buf][A/B][kh][row][col] 128KB
    const int NT = K >> 6;

    const int tid  = threadIdx.x;
    const int wave = tid >> 6;
    const int lane = tid & 63;
    const int quad = lane >> 4;
    const int l16  = lane & 15;
    const int wm = wave >> 2;   // 0..1 -> rows wm*128..+128
    const int wn = wave & 3;    // 0..3 -> cols wn*64..+64

    // T1: bijective XCD-aware swizzle (m204) — contiguous work chunk per XCD
    const int nbm = M >> 8;
    const int nwg = nbm * (N >> 8);
    int wg = blockIdx.x;
    {
        const int q8 = nwg >> 3, r8 = nwg & 7;
        const int xcd = wg & 7, base = wg >> 3;
        wg = (xcd < r8 ? xcd * (q8 + 1) : r8 * (q8 + 1) + (xcd - r8) * q8) + base;
    }
    const int m0 = (wg % nbm) << 8;
    const int n0 = (wg / nbm) << 8;

    const int srow = lane >> 2;        // staging: row within 16-row chunk
    const int scol = (lane & 3) * 8;   // staging: col (elements)

    // stage one 16KB unit: [256][32] of A (matr=0) or B (matr=1), k-half kh.
    // 8 waves x 2 insts x 1KB; lds dest wave-uniform, global src per-lane.
    auto stage = [&](int tile, int matr, int kh) {
        const __hip_bfloat16* g = matr ? B : A;
        const int b0 = matr ? n0 : m0;
        const int buf = tile & 1;
        #pragma unroll
        for (int j = 0; j < 2; ++j) {
            const int c = wave * 2 + j;   // 1KB chunk = rows [c*16, c*16+16)
            async_copy16(g + (size_t)(b0 + c * 16 + srow) * K + tile * 64 + kh * 32 + scol,
                         &sAB[buf][matr][kh][c * 16][0]);
        }
    };

    // prologue: units 0..5 = tile0 {Ak0,Bk0,Ak1,Bk1}, tile1 {Ak0,Bk0}
    stage(0, 0, 0); stage(0, 1, 0); stage(0, 0, 1); stage(0, 1, 1);
    stage(1, 0, 0); stage(1, 1, 0);
    asm volatile("s_waitcnt vmcnt(8)" ::: "memory");   // tile0 kh0 landed (8 insts after it)
    __builtin_amdgcn_s_barrier();

    f32x4 acc[8][4] = {};
    bf16x8 bv[4];

    for (int T = 0; T < NT; ++T) {
        const int buf = T & 1;
        #pragma unroll
        for (int q = 0; q < 4; ++q) {
            const int kh = q >> 1;
            const int rh = (q == 1 || q == 2) ? 1 : 0;   // serpentine: B frags reused q0->q1, q2->q3

            // ds_read register subtile (A: 4x b128 every phase; B: 4x on kh change)
            bf16x8 av[4];
            #pragma unroll
            for (int i = 0; i < 4; ++i)
                av[i] = *(const bf16x8*)&sAB[buf][0][kh][wm * 128 + (rh * 4 + i) * 16 + l16][quad * 8];
            if (q == 0 || q == 2) {
                #pragma unroll
                for (int j = 0; j < 4; ++j)
                    bv[j] = *(const bf16x8*)&sAB[buf][1][kh][wn * 64 + j * 16 + l16][quad * 8];
            }

            // stage unit 4T+q+6 (6 phases ahead; region's readers done >=1 barrier ago)
            if (q == 0) { if (T + 1 < NT) stage(T + 1, 0, 1); }
            if (q == 1) { if (T + 1 < NT) stage(T + 1, 1, 1); }
            if (q == 2) { if (T + 2 < NT) stage(T + 2, 0, 0); }
            if (q == 3) { if (T + 2 < NT) stage(T + 2, 1, 0); }

            __builtin_amdgcn_s_barrier();
            asm volatile("s_waitcnt lgkmcnt(0)" ::: "memory");
            __builtin_amdgcn_s_setprio(1);
            #pragma unroll
            for (int i = 0; i < 4; ++i)
                #pragma unroll
                for (int j = 0; j < 4; ++j)
                    acc[rh * 4 + i][j] = __builtin_amdgcn_mfma_f32_16x16x32_bf16(
                        av[i], bv[j], acc[rh * 4 + i][j], 0, 0, 0);
            __builtin_amdgcn_s_setprio(0);

            if (q == 1) {  // W1: this tile's kh1 (issued 4 phases ago) must be landed for q2/q3
                if (T < NT - 1)       asm volatile("s_waitcnt vmcnt(8)" ::: "memory");
                else                  asm volatile("s_waitcnt vmcnt(0)" ::: "memory");
            }
            if (q == 3) {  // W2: next tile's kh0 (issued 4 phases ago) must be landed for T+1 q0/q1
                if (T < NT - 2)       asm volatile("s_waitcnt vmcnt(8)" ::: "memory");
                else if (T == NT - 2) asm volatile("s_waitcnt vmcnt(4)" ::: "memory");
            }
            __builtin_amdgcn_s_barrier();
        }
    }

    // epilogue: C/D frag mapping col=l16, row=quad*4+r
    #pragma unroll
    for (int i = 0; i < 8; ++i)
        #pragma unroll
        for (int j = 0; j < 4; ++j)
            #pragma unroll
            for (int r = 0; r < 4; ++r) {
                const int m = m0 + wm * 128 + i * 16 + quad * 4 + r;
                const int n = n0 + wn * 64 + j * 16 + l16;
                stc(&C[(size_t)m * N + n], acc[i][j][r]);
            }
}

// ---------------------------------------------------------------------------
// RoPE (in place, bf16). X rows of stride ld; heads start at col0.
// ---------------------------------------------------------------------------
__global__ void rope_kernel(__hip_bfloat16* __restrict__ X, int rows, int n_heads,
                            int ld, int col0)
{
    const int idx = blockIdx.x * blockDim.x + threadIdx.x;
    const int total = rows * n_heads * 64;
    if (idx >= total) return;
    const int j   = idx & 63;
    const int h   = (idx >> 6) % n_heads;
    const int row = idx / (n_heads * 64);
    const int s   = row & (SEQ - 1);

    const float invf = expf(-(float)j * (9.210340371976184f / 64.0f)); // 10000^(-j/64)
    const float ang = (float)s * invf;
    const float c = cosf(ang), sn = sinf(ang);

    const size_t base = (size_t)row * ld + col0 + h * 128;
    const float x1 = __bfloat162float(X[base + j]);
    const float x2 = __bfloat162float(X[base + 64 + j]);
    X[base + j]      = __float2bfloat16(x1 * c - x2 * sn);
    X[base + 64 + j] = __float2bfloat16(x2 * c + x1 * sn);
}

// ---------------------------------------------------------------------------
// V transpose, LDS-tiled: V rows (stride LDQ) -> VT[(b*1024+n)*SEQ + s].
// ---------------------------------------------------------------------------
__global__ __launch_bounds__(256) void vtrans_kernel(
    const __hip_bfloat16* __restrict__ V, __hip_bfloat16* __restrict__ VT)
{
    __shared__ unsigned int T[64][65];   // [s][n], 16.6 KB

    const int tid = threadIdx.x;
    const int n0 = blockIdx.x * 64;
    const int s0 = blockIdx.y * 64;
    const int b  = blockIdx.z;

    #pragma unroll
    for (int it = 0; it < 2; it++) {
        const int idx = it * 256 + tid;
        const int sr = idx >> 3, nc = (idx & 7) * 8;
        const uint4 v = *(const uint4*)(V + (size_t)(b * SEQ + s0 + sr) * LDQ + n0 + nc);
        const unsigned short* u = (const unsigned short*)&v;
        #pragma unroll
        for (int i = 0; i < 8; i++) T[sr][nc + i] = u[i];
    }
    __syncthreads();
    #pragma unroll
    for (int it = 0; it < 2; it++) {
        const int idx = it * 256 + tid;
        const int nn = idx >> 3, sc = (idx & 7) * 8;
        unsigned short u[8];
        #pragma unroll
        for (int i = 0; i < 8; i++) u[i] = (unsigned short)T[sc + i][nn];
        *(uint4*)(VT + (size_t)(b * 1024 + n0 + nn) * SEQ + s0 + sc) = *(const uint4*)u;
    }
}

// ---------------------------------------------------------------------------
// Flash attention (causal, GQA 4:1), bf16, fp32 STATIC-SHIFT softmax.
// ---------------------------------------------------------------------------
__global__ __launch_bounds__(64) void attn_kernel(
    const __hip_bfloat16* __restrict__ QKV,
    const __hip_bfloat16* __restrict__ VT,
    __hip_bfloat16* __restrict__ O)
{
    __shared__ __align__(16) __hip_bfloat16 Pw[2][16][72];  // 4608 B, wave-private

    const int lane = threadIdx.x;
    const int quad = lane >> 4;
    const int l16  = lane & 15;
    const int h   = blockIdx.y;
    const int b   = blockIdx.z;
    const int kvh = h >> 2;

    bf16x8 ones;
    {
        __hip_bfloat16 t[8];
        for (int i = 0; i < 8; i++) t[i] = __float2bfloat16(1.0f);
        ones = *(const bf16x8*)t;
    }

    const __hip_bfloat16* Kbase = QKV + (size_t)b * SEQ * LDQ + 4096 + kvh * 128 + quad * 8;
    const __hip_bfloat16* Vbase = VT + (size_t)(b * 1024 + kvh * 128) * SEQ + quad * 8;
    const float scale = 0.08838834764831845f;  // 1/sqrt(128)
    const float shift = 12.0f;                 // static softmax shift

    for (int ph = 0; ph < 2; ph++) {
        const int qt = ph ? blockIdx.x : 63 - blockIdx.x;  // heavy tile first
        const int q0 = qt * 32;

        bf16x8 aq[2][4];
        for (int ch = 0; ch < 2; ch++)
            for (int c = 0; c < 4; c++)
                aq[ch][c] = *(const bf16x8*)(QKV + (size_t)(b * SEQ + q0 + ch * 16 + l16) * LDQ
                                                 + h * 128 + c * 32 + quad * 8);

        f32x4 o[2][8] = {};
        f32x4 lsum[2] = {};

        const int nt = qt / 2 + 1;
        for (int kt = 0; kt < nt; kt++) {
            f32x4 sc[2][4] = {};
            #pragma unroll
            for (int g = 0; g < 4; g++) {
                const __hip_bfloat16* kr = Kbase + (size_t)(kt * 64 + g * 16 + l16) * LDQ;
                bf16x8 bk[4];
                #pragma unroll
                for (int c = 0; c < 4; c++) bk[c] = *(const bf16x8*)(kr + c * 32);
                #pragma unroll
                for (int c = 0; c < 4; c++) {
                    sc[0][g] = __builtin_amdgcn_mfma_f32_16x16x32_bf16(aq[0][c], bk[c], sc[0][g], 0, 0, 0);
                    sc[1][g] = __builtin_amdgcn_mfma_f32_16x16x32_bf16(aq[1][c], bk[c], sc[1][g], 0, 0, 0);
                }
            }

            const bool diag = (kt == nt - 1);
            #pragma unroll
            for (int ch = 0; ch < 2; ch++)
                #pragma unroll
                for (int rr = 0; rr < 4; rr++) {
                    float s[4];
                    #pragma unroll
                    for (int g = 0; g < 4; g++) s[g] = sc[ch][g][rr] * scale - shift;
                    if (diag) {
                        const int qg = q0 + ch * 16 + quad * 4 + rr;
                        #pragma unroll
                        for (int g = 0; g < 4; g++)
                            if (kt * 64 + g * 16 + l16 > qg) s[g] = -1e30f;
                    }
                    #pragma unroll
                    for (int g = 0; g < 4; g++)
                        Pw[ch][quad * 4 + rr][g * 16 + l16] = __float2bfloat16(__expf(s[g]));
                }
            asm volatile("s_waitcnt lgkmcnt(0)" ::: "memory");

            bf16x8 ap[2][2];
            #pragma unroll
            for (int ch = 0; ch < 2; ch++) {
                ap[ch][0] = *(const bf16x8*)(&Pw[ch][l16][quad * 8]);
                ap[ch][1] = *(const bf16x8*)(&Pw[ch][l16][32 + quad * 8]);
                lsum[ch] = __builtin_amdgcn_mfma_f32_16x16x32_bf16(ap[ch][0], ones, lsum[ch], 0, 0, 0);
                lsum[ch] = __builtin_amdgcn_mfma_f32_16x16x32_bf16(ap[ch][1], ones, lsum[ch], 0, 0, 0);
            }

            #pragma unroll
            for (int nc = 0; nc < 8; nc++) {
                const __hip_bfloat16* vr = Vbase + (size_t)(nc * 16 + l16) * SEQ + kt * 64;
                const bf16x8 bv0 = *(const bf16x8*)(vr);
                const bf16x8 bv1 = *(const bf16x8*)(vr + 32);
                o[0][nc] = __builtin_amdgcn_mfma_f32_16x16x32_bf16(ap[0][0], bv0, o[0][nc], 0, 0, 0);
                o[0][nc] = __builtin_amdgcn_mfma_f32_16x16x32_bf16(ap[0][1], bv1, o[0][nc], 0, 0, 0);
                o[1][nc] = __builtin_amdgcn_mfma_f32_16x16x32_bf16(ap[1][0], bv0, o[1][nc], 0, 0, 0);
                o[1][nc] = __builtin_amdgcn_mfma_f32_16x16x32_bf16(ap[1][1], bv1, o[1][nc], 0, 0, 0);
            }
        }

        for (int ch = 0; ch < 2; ch++)
            for (int rr = 0; rr < 4; rr++) {
                const float inv = 1.0f / lsum[ch][rr];
                const size_t row = (size_t)(b * SEQ + q0 + ch * 16 + quad * 4 + rr);
                for (int nc = 0; nc < 8; nc++)
                    O[row * 4096 + h * 128 + nc * 16 + l16] = __float2bfloat16(o[ch][nc][rr] * inv);
            }
    }
}

// ---------------------------------------------------------------------------
extern "C" void kernel_launch(void* const* d_in, const int* in_sizes, int n_in,
                              void* d_out, int out_size, void* d_ws, size_t ws_size,
                              hipStream_t stream)
{
    const float* X  = (const float*)d_in[0]; // [4096, 4096]
    const float* Wq = (const float*)d_in[1]; // [4096, 4096]
    const float* Wk = (const float*)d_in[2]; // [1024, 4096]
    const float* Wv = (const float*)d_in[3]; // [1024, 4096]
    const float* Wo = (const float*)d_in[4]; // [4096, 4096]
    float* out = (float*)d_out;

    const size_t MB = 1048576;
    char* ws = (char*)d_ws;
    __hip_bfloat16* Xb   = (__hip_bfloat16*)(ws);            // 32MB (later: Ab)
    __hip_bfloat16* WB   = (__hip_bfloat16*)(ws + 32 * MB);  // 48MB: Wq|Wk|Wv fused [6144,4096]
    __hip_bfloat16* Wkb  = (__hip_bfloat16*)(ws + 64 * MB);  //   (rows 4096.. of WB)
    __hip_bfloat16* Wvb  = (__hip_bfloat16*)(ws + 72 * MB);  //   (rows 5120.. of WB)
    __hip_bfloat16* QKVb = (__hip_bfloat16*)(ws + 80 * MB);  // 48MB [4096, 6144]
    __hip_bfloat16* Ab   = Xb;                               // alias (X dead after proj)
    __hip_bfloat16* Wob  = WB;                               // alias (W dead after proj)
    __hip_bfloat16* VT   = Wkb;                              // alias (8MB, after proj)

    const int M = BATCH * SEQ;  // 4096

    // fp32 -> bf16 conversions (weights land contiguously -> one fused B matrix)
    f2b_kernel<<<(M * 4096 / 8 + 255) / 256, 256, 0, stream>>>(X,  Xb,  M * 4096 / 8);
    f2b_kernel<<<(4096 * 4096 / 8 + 255) / 256, 256, 0, stream>>>(Wq, WB,  4096 * 4096 / 8);
    f2b_kernel<<<(1024 * 4096 / 8 + 255) / 256, 256, 0, stream>>>(Wk, Wkb, 1024 * 4096 / 8);
    f2b_kernel<<<(1024 * 4096 / 8 + 255) / 256, 256, 0, stream>>>(Wv, Wvb, 1024 * 4096 / 8);

    // fused QKV projection: [4096,4096] @ [6144,4096]^T -> [4096,6144]
    gemm256_kernel<__hip_bfloat16>
        <<<dim3((M / 256) * (LDQ / 256)), 512, 0, stream>>>(Xb, WB, QKVb, M, LDQ, 4096);

    // Wo conversion into WB's slot (weights dead now)
    f2b_kernel<<<(4096 * 4096 / 8 + 255) / 256, 256, 0, stream>>>(Wo, Wob, 4096 * 4096 / 8);

    // RoPE on Q (cols 0..4095, 32 heads) and K (cols 4096..5119, 8 heads)
    rope_kernel<<<(M * 32 * 64 + 255) / 256, 256, 0, stream>>>(QKVb, M, 32, LDQ, 0);
    rope_kernel<<<(M * 8 * 64 + 255) / 256, 256, 0, stream>>>(QKVb, M, 8, LDQ, 4096);

    // V transpose (V = cols 5120.. of QKVb) into VT  (LDS-tiled)
    vtrans_kernel<<<dim3(16, SEQ / 64, BATCH), 256, 0, stream>>>(QKVb + 5120, VT);

    // causal GQA flash attention -> Ab  (paired q-tiles, 1-wave blocks)
    attn_kernel<<<dim3(32, 32, BATCH), 64, 0, stream>>>(QKVb, VT, Ab);

    // output projection -> d_out (fp32)
    gemm256_kernel<float>
        <<<dim3((M / 256) * (4096 / 256)), 512, 0, stream>>>(Ab, Wob, out, M, 4096, 4096);
}

// Round 4
// 844.589 us; speedup vs baseline: 1.0346x; 1.0346x over previous
//
#include <hip/hip_runtime.h>
#include <hip/hip_bf16.h>

typedef __attribute__((ext_vector_type(8))) __bf16 bf16x8;
typedef __attribute__((ext_vector_type(4))) float f32x4;

#define SEQ 2048
#define BATCH 2
#define LDQ 6144   // QKV row stride: 32 Q heads | 8 K heads | 8 V heads

// ---------------------------------------------------------------------------
// helpers
// ---------------------------------------------------------------------------
__device__ __forceinline__ void stc(float* p, float v)          { *p = v; }
__device__ __forceinline__ void stc(__hip_bfloat16* p, float v) { *p = __float2bfloat16(v); }

// async 16B global->LDS. ldsptr MUST be wave-uniform; HW writes base + lane*16.
__device__ __forceinline__ void async_copy16(const __hip_bfloat16* g, __hip_bfloat16* lds) {
    __builtin_amdgcn_global_load_lds(
        (const __attribute__((address_space(1))) unsigned int*)g,
        (__attribute__((address_space(3))) unsigned int*)lds,
        16, 0, 0);
}

// ---------------------------------------------------------------------------
// fp32 -> bf16 conversion (vectorized, 8 elems/thread)
// ---------------------------------------------------------------------------
__global__ void f2b_kernel(const float* __restrict__ s, __hip_bfloat16* __restrict__ d, int n8)
{
    const int i = blockIdx.x * blockDim.x + threadIdx.x;
    if (i >= n8) return;
    const float4 a = ((const float4*)s)[i * 2];
    const float4 b = ((const float4*)s)[i * 2 + 1];
    __hip_bfloat16 t[8];
    t[0] = __float2bfloat16(a.x); t[1] = __float2bfloat16(a.y);
    t[2] = __float2bfloat16(a.z); t[3] = __float2bfloat16(a.w);
    t[4] = __float2bfloat16(b.x); t[5] = __float2bfloat16(b.y);
    t[6] = __float2bfloat16(b.z); t[7] = __float2bfloat16(b.w);
    ((uint4*)d)[i] = *(const uint4*)t;
}

// ---------------------------------------------------------------------------
// GEMM: C[M,N] = A[M,K] @ B[N,K]^T  (bf16 in, fp32 acc) — 256x256 8-phase
// schedule: BK=64, 512 thr = 8 waves (2Mx4N), per-wave output 128x64.
// LDS 128KB = 2 dbuf x {A,B} x {k0,k1} x [256][32] bf16.
//
// T2 CHUNK-XOR SWIZZLE (r4): in each [256][32] unit (64B rows = 4x16B
// chunks), logical chunk c lives at physical chunk c ^ ((row>>1)&3).
// Read pattern (fixed chunk, 16 consecutive rows) then walks all 8 bank
// clusters per 8-lane group -> zero-conflict ds_read_b128 (was 4-way:
// cluster=(4r)%8 in {0,4} only; SQ_LDS_BANK_CONFLICT 1.9e7 deterministic).
// Rule 21: LDS dest of global_load_lds stays LINEAR; the global SOURCE is
// pre-permuted per lane (each 4-lane group still reads the same contiguous
// 64B -> coalescing preserved). Read offset is lane-constant.
//
// Two-loose-wait vmcnt pipeline (r3): W1 @q1 vmcnt(8) covers tile T kh1
// (issued 4 phases earlier); W2 @q3 vmcnt(8) covers tile T+1 kh0. Tail:
// T=NT-2 W2->vmcnt(4), T=NT-1 W1->vmcnt(0). vmcnt retires in-order.
// ---------------------------------------------------------------------------
template<typename TC>
__global__ __launch_bounds__(512, 2) void gemm256_kernel(
    const __hip_bfloat16* __restrict__ A,
    const __hip_bfloat16* __restrict__ B,
    TC* __restrict__ C,
    int M, int N, int K)
{
    __shared__ __align__(16) __hip_bfloat16 sAB[2][2][2][256][32]; // [buf][A/B][kh][row][col] 128KB
    const int NT = K >> 6;

    const int tid  = threadIdx.x;
    const int wave = tid >> 6;
    const int lane = tid & 63;
    const int quad = lane >> 4;
    const int l16  = lane & 15;
    const int wm = wave >> 2;   // 0..1 -> rows wm*128..+128
    const int wn = wave & 3;    // 0..3 -> cols wn*64..+64

    // T1: bijective XCD-aware swizzle (m204) — contiguous work chunk per XCD
    const int nbm = M >> 8;
    const int nwg = nbm * (N >> 8);
    int wg = blockIdx.x;
    {
        const int q8 = nwg >> 3, r8 = nwg & 7;
        const int xcd = wg & 7, base = wg >> 3;
        wg = (xcd < r8 ? xcd * (q8 + 1) : r8 * (q8 + 1) + (xcd - r8) * q8) + base;
    }
    const int m0 = (wg % nbm) << 8;
    const int n0 = (wg / nbm) << 8;

    const int srow = lane >> 2;                          // staging row within 16-row chunk
    const int scol = ((lane & 3) ^ ((lane >> 3) & 3)) * 8; // staging col, pre-swizzled source
    const int qsw  = (quad ^ ((l16 >> 1) & 3)) * 8;      // swizzled read chunk (lane-constant)

    // stage one 16KB unit: [256][32] of A (matr=0) or B (matr=1), k-half kh.
    // LDS dest linear; global source permuted so swizzled reads see logical data.
    auto stage = [&](int tile, int matr, int kh) {
        const __hip_bfloat16* g = matr ? B : A;
        const int b0 = matr ? n0 : m0;
        const int buf = tile & 1;
        #pragma unroll
        for (int j = 0; j < 2; ++j) {
            const int c = wave * 2 + j;   // 1KB chunk = rows [c*16, c*16+16)
            async_copy16(g + (size_t)(b0 + c * 16 + srow) * K + tile * 64 + kh * 32 + scol,
                         &sAB[buf][matr][kh][c * 16][0]);
        }
    };

    // prologue: units 0..5 = tile0 {Ak0,Bk0,Ak1,Bk1}, tile1 {Ak0,Bk0}
    stage(0, 0, 0); stage(0, 1, 0); stage(0, 0, 1); stage(0, 1, 1);
    stage(1, 0, 0); stage(1, 1, 0);
    asm volatile("s_waitcnt vmcnt(8)" ::: "memory");   // tile0 kh0 landed (8 insts after it)
    __builtin_amdgcn_s_barrier();

    f32x4 acc[8][4] = {};
    bf16x8 bv[4];

    for (int T = 0; T < NT; ++T) {
        const int buf = T & 1;
        #pragma unroll
        for (int q = 0; q < 4; ++q) {
            const int kh = q >> 1;
            const int rh = (q == 1 || q == 2) ? 1 : 0;   // serpentine: B frags reused q0->q1, q2->q3

            // ds_read register subtile (A: 4x b128 every phase; B: 4x on kh change)
            bf16x8 av[4];
            #pragma unroll
            for (int i = 0; i < 4; ++i)
                av[i] = *(const bf16x8*)&sAB[buf][0][kh][wm * 128 + (rh * 4 + i) * 16 + l16][qsw];
            if (q == 0 || q == 2) {
                #pragma unroll
                for (int j = 0; j < 4; ++j)
                    bv[j] = *(const bf16x8*)&sAB[buf][1][kh][wn * 64 + j * 16 + l16][qsw];
            }

            // stage unit 4T+q+6 (6 phases ahead; region's readers done >=1 barrier ago)
            if (q == 0) { if (T + 1 < NT) stage(T + 1, 0, 1); }
            if (q == 1) { if (T + 1 < NT) stage(T + 1, 1, 1); }
            if (q == 2) { if (T + 2 < NT) stage(T + 2, 0, 0); }
            if (q == 3) { if (T + 2 < NT) stage(T + 2, 1, 0); }

            __builtin_amdgcn_s_barrier();
            asm volatile("s_waitcnt lgkmcnt(0)" ::: "memory");
            __builtin_amdgcn_s_setprio(1);
            #pragma unroll
            for (int i = 0; i < 4; ++i)
                #pragma unroll
                for (int j = 0; j < 4; ++j)
                    acc[rh * 4 + i][j] = __builtin_amdgcn_mfma_f32_16x16x32_bf16(
                        av[i], bv[j], acc[rh * 4 + i][j], 0, 0, 0);
            __builtin_amdgcn_s_setprio(0);

            if (q == 1) {  // W1: this tile's kh1 (issued 4 phases ago) must be landed for q2/q3
                if (T < NT - 1)       asm volatile("s_waitcnt vmcnt(8)" ::: "memory");
                else                  asm volatile("s_waitcnt vmcnt(0)" ::: "memory");
            }
            if (q == 3) {  // W2: next tile's kh0 (issued 4 phases ago) must be landed for T+1 q0/q1
                if (T < NT - 2)       asm volatile("s_waitcnt vmcnt(8)" ::: "memory");
                else if (T == NT - 2) asm volatile("s_waitcnt vmcnt(4)" ::: "memory");
            }
            __builtin_amdgcn_s_barrier();
        }
    }

    // epilogue: C/D frag mapping col=l16, row=quad*4+r
    #pragma unroll
    for (int i = 0; i < 8; ++i)
        #pragma unroll
        for (int j = 0; j < 4; ++j)
            #pragma unroll
            for (int r = 0; r < 4; ++r) {
                const int m = m0 + wm * 128 + i * 16 + quad * 4 + r;
                const int n = n0 + wn * 64 + j * 16 + l16;
                stc(&C[(size_t)m * N + n], acc[i][j][r]);
            }
}

// ---------------------------------------------------------------------------
// RoPE (in place, bf16). X rows of stride ld; heads start at col0.
// ---------------------------------------------------------------------------
__global__ void rope_kernel(__hip_bfloat16* __restrict__ X, int rows, int n_heads,
                            int ld, int col0)
{
    const int idx = blockIdx.x * blockDim.x + threadIdx.x;
    const int total = rows * n_heads * 64;
    if (idx >= total) return;
    const int j   = idx & 63;
    const int h   = (idx >> 6) % n_heads;
    const int row = idx / (n_heads * 64);
    const int s   = row & (SEQ - 1);

    const float invf = expf(-(float)j * (9.210340371976184f / 64.0f)); // 10000^(-j/64)
    const float ang = (float)s * invf;
    const float c = cosf(ang), sn = sinf(ang);

    const size_t base = (size_t)row * ld + col0 + h * 128;
    const float x1 = __bfloat162float(X[base + j]);
    const float x2 = __bfloat162float(X[base + 64 + j]);
    X[base + j]      = __float2bfloat16(x1 * c - x2 * sn);
    X[base + 64 + j] = __float2bfloat16(x2 * c + x1 * sn);
}

// ---------------------------------------------------------------------------
// V transpose, LDS-tiled: V rows (stride LDQ) -> VT[(b*1024+n)*SEQ + s].
// ---------------------------------------------------------------------------
__global__ __launch_bounds__(256) void vtrans_kernel(
    const __hip_bfloat16* __restrict__ V, __hip_bfloat16* __restrict__ VT)
{
    __shared__ unsigned int T[64][65];   // [s][n], 16.6 KB

    const int tid = threadIdx.x;
    const int n0 = blockIdx.x * 64;
    const int s0 = blockIdx.y * 64;
    const int b  = blockIdx.z;

    #pragma unroll
    for (int it = 0; it < 2; it++) {
        const int idx = it * 256 + tid;
        const int sr = idx >> 3, nc = (idx & 7) * 8;
        const uint4 v = *(const uint4*)(V + (size_t)(b * SEQ + s0 + sr) * LDQ + n0 + nc);
        const unsigned short* u = (const unsigned short*)&v;
        #pragma unroll
        for (int i = 0; i < 8; i++) T[sr][nc + i] = u[i];
    }
    __syncthreads();
    #pragma unroll
    for (int it = 0; it < 2; it++) {
        const int idx = it * 256 + tid;
        const int nn = idx >> 3, sc = (idx & 7) * 8;
        unsigned short u[8];
        #pragma unroll
        for (int i = 0; i < 8; i++) u[i] = (unsigned short)T[sc + i][nn];
        *(uint4*)(VT + (size_t)(b * 1024 + n0 + nn) * SEQ + s0 + sc) = *(const uint4*)u;
    }
}

// ---------------------------------------------------------------------------
// Flash attention (causal, GQA 4:1), bf16, fp32 STATIC-SHIFT softmax.
// ---------------------------------------------------------------------------
__global__ __launch_bounds__(64) void attn_kernel(
    const __hip_bfloat16* __restrict__ QKV,
    const __hip_bfloat16* __restrict__ VT,
    __hip_bfloat16* __restrict__ O)
{
    __shared__ __align__(16) __hip_bfloat16 Pw[2][16][72];  // 4608 B, wave-private

    const int lane = threadIdx.x;
    const int quad = lane >> 4;
    const int l16  = lane & 15;
    const int h   = blockIdx.y;
    const int b   = blockIdx.z;
    const int kvh = h >> 2;

    bf16x8 ones;
    {
        __hip_bfloat16 t[8];
        for (int i = 0; i < 8; i++) t[i] = __float2bfloat16(1.0f);
        ones = *(const bf16x8*)t;
    }

    const __hip_bfloat16* Kbase = QKV + (size_t)b * SEQ * LDQ + 4096 + kvh * 128 + quad * 8;
    const __hip_bfloat16* Vbase = VT + (size_t)(b * 1024 + kvh * 128) * SEQ + quad * 8;
    const float scale = 0.08838834764831845f;  // 1/sqrt(128)
    const float shift = 12.0f;                 // static softmax shift

    for (int ph = 0; ph < 2; ph++) {
        const int qt = ph ? blockIdx.x : 63 - blockIdx.x;  // heavy tile first
        const int q0 = qt * 32;

        bf16x8 aq[2][4];
        for (int ch = 0; ch < 2; ch++)
            for (int c = 0; c < 4; c++)
                aq[ch][c] = *(const bf16x8*)(QKV + (size_t)(b * SEQ + q0 + ch * 16 + l16) * LDQ
                                                 + h * 128 + c * 32 + quad * 8);

        f32x4 o[2][8] = {};
        f32x4 lsum[2] = {};

        const int nt = qt / 2 + 1;
        for (int kt = 0; kt < nt; kt++) {
            f32x4 sc[2][4] = {};
            #pragma unroll
            for (int g = 0; g < 4; g++) {
                const __hip_bfloat16* kr = Kbase + (size_t)(kt * 64 + g * 16 + l16) * LDQ;
                bf16x8 bk[4];
                #pragma unroll
                for (int c = 0; c < 4; c++) bk[c] = *(const bf16x8*)(kr + c * 32);
                #pragma unroll
                for (int c = 0; c < 4; c++) {
                    sc[0][g] = __builtin_amdgcn_mfma_f32_16x16x32_bf16(aq[0][c], bk[c], sc[0][g], 0, 0, 0);
                    sc[1][g] = __builtin_amdgcn_mfma_f32_16x16x32_bf16(aq[1][c], bk[c], sc[1][g], 0, 0, 0);
                }
            }

            const bool diag = (kt == nt - 1);
            #pragma unroll
            for (int ch = 0; ch < 2; ch++)
                #pragma unroll
                for (int rr = 0; rr < 4; rr++) {
                    float s[4];
                    #pragma unroll
                    for (int g = 0; g < 4; g++) s[g] = sc[ch][g][rr] * scale - shift;
                    if (diag) {
                        const int qg = q0 + ch * 16 + quad * 4 + rr;
                        #pragma unroll
                        for (int g = 0; g < 4; g++)
                            if (kt * 64 + g * 16 + l16 > qg) s[g] = -1e30f;
                    }
                    #pragma unroll
                    for (int g = 0; g < 4; g++)
                        Pw[ch][quad * 4 + rr][g * 16 + l16] = __float2bfloat16(__expf(s[g]));
                }
            asm volatile("s_waitcnt lgkmcnt(0)" ::: "memory");

            bf16x8 ap[2][2];
            #pragma unroll
            for (int ch = 0; ch < 2; ch++) {
                ap[ch][0] = *(const bf16x8*)(&Pw[ch][l16][quad * 8]);
                ap[ch][1] = *(const bf16x8*)(&Pw[ch][l16][32 + quad * 8]);
                lsum[ch] = __builtin_amdgcn_mfma_f32_16x16x32_bf16(ap[ch][0], ones, lsum[ch], 0, 0, 0);
                lsum[ch] = __builtin_amdgcn_mfma_f32_16x16x32_bf16(ap[ch][1], ones, lsum[ch], 0, 0, 0);
            }

            #pragma unroll
            for (int nc = 0; nc < 8; nc++) {
                const __hip_bfloat16* vr = Vbase + (size_t)(nc * 16 + l16) * SEQ + kt * 64;
                const bf16x8 bv0 = *(const bf16x8*)(vr);
                const bf16x8 bv1 = *(const bf16x8*)(vr + 32);
                o[0][nc] = __builtin_amdgcn_mfma_f32_16x16x32_bf16(ap[0][0], bv0, o[0][nc], 0, 0, 0);
                o[0][nc] = __builtin_amdgcn_mfma_f32_16x16x32_bf16(ap[0][1], bv1, o[0][nc], 0, 0, 0);
                o[1][nc] = __builtin_amdgcn_mfma_f32_16x16x32_bf16(ap[1][0], bv0, o[1][nc], 0, 0, 0);
                o[1][nc] = __builtin_amdgcn_mfma_f32_16x16x32_bf16(ap[1][1], bv1, o[1][nc], 0, 0, 0);
            }
        }

        for (int ch = 0; ch < 2; ch++)
            for (int rr = 0; rr < 4; rr++) {
                const float inv = 1.0f / lsum[ch][rr];
                const size_t row = (size_t)(b * SEQ + q0 + ch * 16 + quad * 4 + rr);
                for (int nc = 0; nc < 8; nc++)
                    O[row * 4096 + h * 128 + nc * 16 + l16] = __float2bfloat16(o[ch][nc][rr] * inv);
            }
    }
}

// ---------------------------------------------------------------------------
extern "C" void kernel_launch(void* const* d_in, const int* in_sizes, int n_in,
                              void* d_out, int out_size, void* d_ws, size_t ws_size,
                              hipStream_t stream)
{
    const float* X  = (const float*)d_in[0]; // [4096, 4096]
    const float* Wq = (const float*)d_in[1]; // [4096, 4096]
    const float* Wk = (const float*)d_in[2]; // [1024, 4096]
    const float* Wv = (const float*)d_in[3]; // [1024, 4096]
    const float* Wo = (const float*)d_in[4]; // [4096, 4096]
    float* out = (float*)d_out;

    const size_t MB = 1048576;
    char* ws = (char*)d_ws;
    __hip_bfloat16* Xb   = (__hip_bfloat16*)(ws);            // 32MB (later: Ab)
    __hip_bfloat16* WB   = (__hip_bfloat16*)(ws + 32 * MB);  // 48MB: Wq|Wk|Wv fused [6144,4096]
    __hip_bfloat16* Wkb  = (__hip_bfloat16*)(ws + 64 * MB);  //   (rows 4096.. of WB)
    __hip_bfloat16* Wvb  = (__hip_bfloat16*)(ws + 72 * MB);  //   (rows 5120.. of WB)
    __hip_bfloat16* QKVb = (__hip_bfloat16*)(ws + 80 * MB);  // 48MB [4096, 6144]
    __hip_bfloat16* Ab   = Xb;                               // alias (X dead after proj)
    __hip_bfloat16* Wob  = WB;                               // alias (W dead after proj)
    __hip_bfloat16* VT   = Wkb;                              // alias (8MB, after proj)

    const int M = BATCH * SEQ;  // 4096

    // fp32 -> bf16 conversions (weights land contiguously -> one fused B matrix)
    f2b_kernel<<<(M * 4096 / 8 + 255) / 256, 256, 0, stream>>>(X,  Xb,  M * 4096 / 8);
    f2b_kernel<<<(4096 * 4096 / 8 + 255) / 256, 256, 0, stream>>>(Wq, WB,  4096 * 4096 / 8);
    f2b_kernel<<<(1024 * 4096 / 8 + 255) / 256, 256, 0, stream>>>(Wk, Wkb, 1024 * 4096 / 8);
    f2b_kernel<<<(1024 * 4096 / 8 + 255) / 256, 256, 0, stream>>>(Wv, Wvb, 1024 * 4096 / 8);

    // fused QKV projection: [4096,4096] @ [6144,4096]^T -> [4096,6144]
    gemm256_kernel<__hip_bfloat16>
        <<<dim3((M / 256) * (LDQ / 256)), 512, 0, stream>>>(Xb, WB, QKVb, M, LDQ, 4096);

    // Wo conversion into WB's slot (weights dead now)
    f2b_kernel<<<(4096 * 4096 / 8 + 255) / 256, 256, 0, stream>>>(Wo, Wob, 4096 * 4096 / 8);

    // RoPE on Q (cols 0..4095, 32 heads) and K (cols 4096..5119, 8 heads)
    rope_kernel<<<(M * 32 * 64 + 255) / 256, 256, 0, stream>>>(QKVb, M, 32, LDQ, 0);
    rope_kernel<<<(M * 8 * 64 + 255) / 256, 256, 0, stream>>>(QKVb, M, 8, LDQ, 4096);

    // V transpose (V = cols 5120.. of QKVb) into VT  (LDS-tiled)
    vtrans_kernel<<<dim3(16, SEQ / 64, BATCH), 256, 0, stream>>>(QKVb + 5120, VT);

    // causal GQA flash attention -> Ab  (paired q-tiles, 1-wave blocks)
    attn_kernel<<<dim3(32, 32, BATCH), 64, 0, stream>>>(QKVb, VT, Ab);

    // output projection -> d_out (fp32)
    gemm256_kernel<float>
        <<<dim3((M / 256) * (4096 / 256)), 512, 0, stream>>>(Ab, Wob, out, M, 4096, 4096);
}